// Round 9
// baseline (236.020 us; speedup 1.0000x reference)
//
#include <hip/hip_runtime.h>
#include <hip/hip_bf16.h>
#include <hip/hip_cooperative_groups.h>

#define GAMMA 0.9865f

typedef __attribute__((ext_vector_type(8))) short bf16x8;
typedef __attribute__((ext_vector_type(4))) float f32x4;

static constexpr int Bb  = 8;
static constexpr int Tt  = 2048;
static constexpr int DIN = 1024;
static constexpr int Dd  = 1024;
static constexpr int Mm  = Bb * Tt;      // 16384
static constexpr int CL  = 64;           // chunk length for scan
static constexpr int NC  = Tt / CL;      // 32 chunks
static constexpr int NT  = DIN / 64;     // 16 K-tiles of BK=64

__device__ __forceinline__ void gload16(const void* g, void* l) {
  __builtin_amdgcn_global_load_lds(
      (const __attribute__((address_space(1))) void*)g,
      (__attribute__((address_space(3))) void*)l, 16, 0, 0);
}

__device__ __forceinline__ void bar() {
  asm volatile("" ::: "memory");
  __builtin_amdgcn_s_barrier();
  asm volatile("" ::: "memory");
}

__device__ __forceinline__ float bflo(unsigned int u) {
  return __uint_as_float((u & 0xffffu) << 16);
}
__device__ __forceinline__ float bfhi(unsigned int u) {
  return __uint_as_float(u & 0xffff0000u);
}

// ---- K1: merged prep: wsum (blocks 0..255) + Wt transpose (256..2303) ----
__global__ __launch_bounds__(256) void prep_kernel(
    const float* __restrict__ Wq, const float* __restrict__ Wk,
    const float* __restrict__ Wv, float* __restrict__ wsum,
    __hip_bfloat16* __restrict__ Wt) {
  int bid = blockIdx.x;
  if (bid < 256) {
    // wsum[d] = sum_e Wk[d][e]
    int row  = bid * 4 + (threadIdx.x >> 6);
    int lane = threadIdx.x & 63;
    const float4* rp = (const float4*)(Wk + (size_t)row * DIN);
    float s = 0.f;
#pragma unroll
    for (int i = 0; i < 4; ++i) {
      float4 v = rp[lane + i * 64];
      s += v.x + v.y + v.z + v.w;
    }
    for (int off = 32; off; off >>= 1) s += __shfl_down(s, off);
    if (lane == 0) wsum[row] = s;
    return;
  }
  // Wt[n][k] = bf16(W[k][n])
  int wid = bid - 256;
  int z = wid >> 10, rem = wid & 1023;
  int kb = rem & 31, nb = rem >> 5;
  const float* W = z ? Wv : Wq;
  __hip_bfloat16* outp = Wt + (size_t)z * DIN * Dd;
  __shared__ float tile[32][33];
  int k0 = kb * 32, n0 = nb * 32;
  int tx = threadIdx.x & 31, ty = threadIdx.x >> 5;  // (32,8)
#pragma unroll
  for (int i = 0; i < 4; ++i)
    tile[ty + i * 8][tx] = W[(size_t)(k0 + ty + i * 8) * Dd + n0 + tx];
  __syncthreads();
#pragma unroll
  for (int i = 0; i < 4; ++i)
    outp[(size_t)(n0 + ty + i * 8) * DIN + k0 + tx] =
        __float2bfloat16(tile[tx][ty + i * 8]);
}

// ---- K2: cast fp32 -> bf16, 16B stores (R7 known-good) -------------------
__global__ __launch_bounds__(256) void cast_kernel(
    const float* __restrict__ xq, const float* __restrict__ xv,
    __hip_bfloat16* __restrict__ oq, __hip_bfloat16* __restrict__ ov) {
  const float* src = blockIdx.y ? xv : xq;
  __hip_bfloat16* dst = blockIdx.y ? ov : oq;
  size_t i = (size_t)blockIdx.x * 256 + threadIdx.x;  // 8-float group index
  const float4* p = (const float4*)src;
  float4 a = p[i * 2], b = p[i * 2 + 1];
  union { __hip_bfloat16 h[8]; bf16x8 v; } u;
  u.h[0] = __float2bfloat16(a.x); u.h[1] = __float2bfloat16(a.y);
  u.h[2] = __float2bfloat16(a.z); u.h[3] = __float2bfloat16(a.w);
  u.h[4] = __float2bfloat16(b.x); u.h[5] = __float2bfloat16(b.y);
  u.h[6] = __float2bfloat16(b.z); u.h[7] = __float2bfloat16(b.w);
  ((bf16x8*)dst)[i] = u.v;
}

// ---- K3: 256x256 8-phase bf16 MFMA GEMM (T2+T3+T4+T5) — R7 known-good ----
__device__ __forceinline__ void stage_half(const __hip_bfloat16* g, char* l, int tid) {
#pragma unroll
  for (int j = 0; j < 2; ++j) {
    int c = tid + j * 512;
    int row = c >> 3, ch = c & 7;
    gload16(g + (size_t)row * DIN + ((ch ^ (row & 7)) << 3), l + c * 16);
  }
}

__device__ __forceinline__ bf16x8 lds_frag(const char* base, int row, int kc) {
  return *(const bf16x8*)(base + (((row << 3) + (kc ^ (row & 7))) << 4));
}

#define MFMA_QUAD(MLO, NLO)                                                  \
  _Pragma("unroll") for (int mi = 0; mi < 4; ++mi)                           \
  _Pragma("unroll") for (int ni = 0; ni < 2; ++ni)                           \
  _Pragma("unroll") for (int ks = 0; ks < 2; ++ks)                           \
      acc[(MLO) + mi][(NLO) + ni] = __builtin_amdgcn_mfma_f32_16x16x32_bf16( \
          a[(MLO) + mi][ks], b[(NLO) + ni][ks], acc[(MLO) + mi][(NLO) + ni], 0, 0, 0);

__global__ __launch_bounds__(512, 2) void gemm8_kernel(
    const __hip_bfloat16* __restrict__ Aq, const __hip_bfloat16* __restrict__ Av,
    const __hip_bfloat16* __restrict__ Wt,
    __hip_bfloat16* __restrict__ Qbf, __hip_bfloat16* __restrict__ Vbf) {
  extern __shared__ char lds[];  // [2][A 32KB | B 32KB]

  // XCD-bijective swizzle: 512 blocks, 512 % 8 == 0
  int lin = blockIdx.x;
  int wg  = (lin & 7) * 64 + (lin >> 3);
  int z   = wg >> 8, rem = wg & 255;
  int by  = rem & 3, bx = rem >> 2;

  const __hip_bfloat16* Ab = z ? Av : Aq;
  const int m0 = bx * 256, n0 = by * 256;
  const __hip_bfloat16* Ag = Ab + (size_t)m0 * DIN;
  const __hip_bfloat16* Bg = Wt + ((size_t)z * Dd + n0) * DIN;
  __hip_bfloat16* Cc = z ? Vbf : Qbf;

  const int tid = threadIdx.x;
  const int wv = tid >> 6, lane = tid & 63;
  const int wm = (wv >> 2) * 128, wn = (wv & 3) * 64;
  const int fq = lane >> 4, fr = lane & 15;

  f32x4 acc[8][4] = {};

  // prologue: tile0 (A+B), tile1 (A only; its B staged during tile0 phases)
  stage_half(Ag,                  lds,                 tid);
  stage_half(Ag + 128 * DIN,      lds + 16384,         tid);
  stage_half(Bg,                  lds + 32768,         tid);
  stage_half(Bg + 128 * DIN,      lds + 49152,         tid);
  stage_half(Ag + 64,             lds + 65536,         tid);
  stage_half(Ag + 128 * DIN + 64, lds + 65536 + 16384, tid);
  asm volatile("s_waitcnt vmcnt(4)" ::: "memory");
  bar();

  for (int t = 0; t < NT; ++t) {
    char* buf  = lds + (t & 1) * 65536;
    char* bufN = lds + ((t + 1) & 1) * 65536;
    const char* At = buf;
    const char* Bt = buf + 32768;
    bf16x8 a[8][2], b[4][2];

    // ---- P0: read a[0..3], b[0..1]; stage B(t+1)h0
#pragma unroll
    for (int mi = 0; mi < 4; ++mi)
#pragma unroll
      for (int ks = 0; ks < 2; ++ks)
        a[mi][ks] = lds_frag(At, wm + mi * 16 + fr, ks * 4 + fq);
#pragma unroll
    for (int ni = 0; ni < 2; ++ni)
#pragma unroll
      for (int ks = 0; ks < 2; ++ks)
        b[ni][ks] = lds_frag(Bt, wn + ni * 16 + fr, ks * 4 + fq);
    if (t + 1 < NT) stage_half(Bg + (size_t)(t + 1) * 64, bufN + 32768, tid);
    bar();
    __builtin_amdgcn_s_setprio(1);
    MFMA_QUAD(0, 0);
    __builtin_amdgcn_s_setprio(0);
    bar();

    // ---- P1: read a[4..7]; stage B(t+1)h1
#pragma unroll
    for (int mi = 4; mi < 8; ++mi)
#pragma unroll
      for (int ks = 0; ks < 2; ++ks)
        a[mi][ks] = lds_frag(At, wm + mi * 16 + fr, ks * 4 + fq);
    if (t + 1 < NT)
      stage_half(Bg + 128 * DIN + (size_t)(t + 1) * 64, bufN + 49152, tid);
    bar();
    __builtin_amdgcn_s_setprio(1);
    MFMA_QUAD(4, 0);
    __builtin_amdgcn_s_setprio(0);
    bar();

    // ---- P2: read b[2..3]; stage A(t+2)h0 into buf (A dead after P1)
#pragma unroll
    for (int ni = 2; ni < 4; ++ni)
#pragma unroll
      for (int ks = 0; ks < 2; ++ks)
        b[ni][ks] = lds_frag(Bt, wn + ni * 16 + fr, ks * 4 + fq);
    if (t + 2 < NT) stage_half(Ag + (size_t)(t + 2) * 64, buf, tid);
    bar();
    __builtin_amdgcn_s_setprio(1);
    MFMA_QUAD(0, 2);
    __builtin_amdgcn_s_setprio(0);
    bar();

    // ---- P3: stage A(t+2)h1; counted vmcnt once per tile (T4)
    if (t + 2 < NT)
      stage_half(Ag + 128 * DIN + (size_t)(t + 2) * 64, buf + 16384, tid);
    if (t + 1 < NT) {
      if (t + 2 < NT) asm volatile("s_waitcnt vmcnt(4)" ::: "memory");
      else            asm volatile("s_waitcnt vmcnt(0)" ::: "memory");
    }
    bar();
    __builtin_amdgcn_s_setprio(1);
    MFMA_QUAD(4, 2);
    __builtin_amdgcn_s_setprio(0);
    bar();
  }

  // epilogue: C/D layout col=lane&15, row=(lane>>4)*4+reg
#pragma unroll
  for (int mi = 0; mi < 8; ++mi) {
#pragma unroll
    for (int ni = 0; ni < 4; ++ni) {
      f32x4 v = acc[mi][ni];
      int row = m0 + wm + mi * 16 + fq * 4;
      int col = n0 + wn + ni * 16 + fr;
#pragma unroll
      for (int j = 0; j < 4; ++j)
        Cc[(size_t)(row + j) * Dd + col] = __float2bfloat16(v[j]);
    }
  }
}

// ---- K4: ksum[i] = dot(xk[i,:], wsum) fp32 (R7 known-good) ---------------
__global__ void ksum_kernel(const float* __restrict__ xk, const float* __restrict__ wsum,
                            float* __restrict__ ksum) {
  int row  = blockIdx.x * 4 + (threadIdx.x >> 6);
  int lane = threadIdx.x & 63;
  const float4* rp = (const float4*)(xk + (size_t)row * DIN);
  const float4* wp = (const float4*)wsum;
  float s = 0.f;
#pragma unroll
  for (int i = 0; i < 4; ++i) {
    float4 a = rp[lane + i * 64];
    float4 w = wp[lane + i * 64];
    s += a.x * w.x + a.y * w.y + a.z * w.z + a.w * w.w;
  }
  for (int off = 32; off; off >>= 1) s += __shfl_down(s, off);
  if (lane == 0) ksum[row] = s;
}

// ---- K5: cooperative fused scanA + scanB + final -------------------------
// 256 blocks x 512 thr (co-resident). Thread owns (b, c, d-pair); V stashed
// in 64 VGPRs across phases (no V re-read in phase 3).
__global__ __launch_bounds__(512) void scanfused_kernel(
    const __hip_bfloat16* __restrict__ Vbf, const __hip_bfloat16* __restrict__ Qbf,
    const float* __restrict__ ksum, float2* __restrict__ E2,
    float2* __restrict__ carry2, float gCL, float* __restrict__ outp) {
  cooperative_groups::grid_group grid = cooperative_groups::this_grid();
  int id = blockIdx.x * 512 + threadIdx.x;  // 131072 = 8b * 32c * 512 d-pairs
  int d2 = id & 511, c = (id >> 9) & 31, b = id >> 14;
  const unsigned int* Vw = (const unsigned int*)Vbf;  // 2 bf16 per word
  size_t base = ((size_t)(b * Tt + c * CL)) * 512 + d2;
  const float* kp = ksum + b * Tt + c * CL;

  unsigned int vs[64];
  float s0 = 0.f, s1 = 0.f;
#pragma unroll
  for (int t = 0; t < CL; ++t) {
    unsigned int w = Vw[base + (size_t)t * 512];
    vs[t] = w;
    float kv = kp[t];
    if (c == 0 && t == 0) kv = 0.f;
    s0 = s0 * GAMMA + kv * bflo(w);
    s1 = s1 * GAMMA + kv * bfhi(w);
  }
  E2[((size_t)b * NC + c) * 512 + d2] = make_float2(s0, s1);

  grid.sync();

  if (id < 4096) {  // (b, d-pair) carry composition over 32 chunks
    int bb = id >> 9, dd = id & 511;
    float t0 = 0.f, t1 = 0.f;
    for (int cc = 0; cc < NC; ++cc) {
      size_t ix = ((size_t)bb * NC + cc) * 512 + dd;
      float2 e = E2[ix];
      carry2[ix] = make_float2(t0, t1);
      t0 = e.x + gCL * t0;
      t1 = e.y + gCL * t1;
    }
  }

  grid.sync();

  float2 cr = carry2[((size_t)b * NC + c) * 512 + d2];
  s0 = cr.x; s1 = cr.y;
  const unsigned int* Qw = (const unsigned int*)Qbf;
  float2* Ow = (float2*)outp;
#pragma unroll
  for (int t = 0; t < CL; ++t) {
    unsigned int w = vs[t];
    float kv = kp[t];
    if (c == 0 && t == 0) kv = 0.f;
    s0 = s0 * GAMMA + kv * bflo(w);
    s1 = s1 * GAMMA + kv * bfhi(w);
    unsigned int qw = Qw[base + (size_t)t * 512];
    Ow[base + (size_t)t * 512] = make_float2(bflo(qw) * s0, bfhi(qw) * s1);
  }
}

extern "C" void kernel_launch(void* const* d_in, const int* in_sizes, int n_in,
                              void* d_out, int out_size, void* d_ws, size_t ws_size,
                              hipStream_t stream) {
  (void)in_sizes; (void)n_in; (void)out_size; (void)ws_size;
  const float* xq = (const float*)d_in[0];
  const float* xk = (const float*)d_in[1];
  const float* xv = (const float*)d_in[2];
  const float* Wq = (const float*)d_in[3];
  const float* Wk = (const float*)d_in[4];
  const float* Wv = (const float*)d_in[5];
  float* outp = (float*)d_out;

  char* ws = (char*)d_ws;
  size_t off = 0;
  auto alloc = [&](size_t bytes) {
    char* p = ws + off;
    off += (bytes + 255) & ~(size_t)255;
    return p;
  };
  __hip_bfloat16* xq_bf = (__hip_bfloat16*)alloc((size_t)Mm * DIN * 2);
  __hip_bfloat16* xv_bf = (__hip_bfloat16*)alloc((size_t)Mm * DIN * 2);
  __hip_bfloat16* Wt    = (__hip_bfloat16*)alloc((size_t)2 * DIN * Dd * 2);
  __hip_bfloat16* Qbf   = (__hip_bfloat16*)alloc((size_t)Mm * Dd * 2);
  __hip_bfloat16* Vbf   = (__hip_bfloat16*)alloc((size_t)Mm * Dd * 2);
  float* wsum   = (float*)alloc((size_t)DIN * 4);
  float* ksum   = (float*)alloc((size_t)Mm * 4);
  float2* E2    = (float2*)alloc((size_t)Bb * NC * 512 * 8);
  float2* carry2= (float2*)alloc((size_t)Bb * NC * 512 * 8);

  double g = 1.0;
  for (int i = 0; i < CL; ++i) g *= (double)GAMMA;
  float gCL = (float)g;

  (void)hipFuncSetAttribute((const void*)gemm8_kernel,
                            hipFuncAttributeMaxDynamicSharedMemorySize, 131072);

  prep_kernel<<<256 + 2048, 256, 0, stream>>>(Wq, Wk, Wv, wsum, Wt);
  cast_kernel<<<dim3(Mm * DIN / 8 / 256, 2), 256, 0, stream>>>(xq, xv, xq_bf, xv_bf);
  ksum_kernel<<<Mm / 4, 256, 0, stream>>>(xk, wsum, ksum);
  gemm8_kernel<<<512, 512, 131072, stream>>>(xq_bf, xv_bf, Wt, Qbf, Vbf);

  const __hip_bfloat16* Vc = Vbf; const __hip_bfloat16* Qc = Qbf;
  const float* kc = ksum;
  void* cargs[] = { (void*)&Vc, (void*)&Qc, (void*)&kc, (void*)&E2,
                    (void*)&carry2, (void*)&gCL, (void*)&outp };
  (void)hipLaunchCooperativeKernel((const void*)scanfused_kernel,
                                   dim3(256), dim3(512), cargs, 0, stream);
}

// Round 10
// 173.192 us; speedup vs baseline: 1.3628x; 1.3628x over previous
//
#include <hip/hip_runtime.h>
#include <hip/hip_bf16.h>

#define GAMMA 0.9865f

typedef __attribute__((ext_vector_type(8))) short bf16x8;
typedef __attribute__((ext_vector_type(4))) float f32x4;

static constexpr int Bb  = 8;
static constexpr int Tt  = 2048;
static constexpr int DIN = 1024;
static constexpr int Dd  = 1024;
static constexpr int Mm  = Bb * Tt;      // 16384
static constexpr int CL  = 64;           // chunk length for scan
static constexpr int NC  = Tt / CL;      // 32 chunks
static constexpr int NT  = DIN / 64;     // 16 K-tiles of BK=64

__device__ __forceinline__ void gload16(const void* g, void* l) {
  __builtin_amdgcn_global_load_lds(
      (const __attribute__((address_space(1))) void*)g,
      (__attribute__((address_space(3))) void*)l, 16, 0, 0);
}

__device__ __forceinline__ void bar() {
  asm volatile("" ::: "memory");
  __builtin_amdgcn_s_barrier();
  asm volatile("" ::: "memory");
}

// ---- K1: merged prep: wsum (blocks 0..255) + Wt transpose (256..2303) ----
__global__ __launch_bounds__(256) void prep_kernel(
    const float* __restrict__ Wq, const float* __restrict__ Wk,
    const float* __restrict__ Wv, float* __restrict__ wsum,
    __hip_bfloat16* __restrict__ Wt) {
  int bid = blockIdx.x;
  if (bid < 256) {
    int row  = bid * 4 + (threadIdx.x >> 6);
    int lane = threadIdx.x & 63;
    const float4* rp = (const float4*)(Wk + (size_t)row * DIN);
    float s = 0.f;
#pragma unroll
    for (int i = 0; i < 4; ++i) {
      float4 v = rp[lane + i * 64];
      s += v.x + v.y + v.z + v.w;
    }
    for (int off = 32; off; off >>= 1) s += __shfl_down(s, off);
    if (lane == 0) wsum[row] = s;
    return;
  }
  int wid = bid - 256;
  int z = wid >> 10, rem = wid & 1023;
  int kb = rem & 31, nb = rem >> 5;
  const float* W = z ? Wv : Wq;
  __hip_bfloat16* outp = Wt + (size_t)z * DIN * Dd;
  __shared__ float tile[32][33];
  int k0 = kb * 32, n0 = nb * 32;
  int tx = threadIdx.x & 31, ty = threadIdx.x >> 5;
#pragma unroll
  for (int i = 0; i < 4; ++i)
    tile[ty + i * 8][tx] = W[(size_t)(k0 + ty + i * 8) * Dd + n0 + tx];
  __syncthreads();
#pragma unroll
  for (int i = 0; i < 4; ++i)
    outp[(size_t)(n0 + ty + i * 8) * DIN + k0 + tx] =
        __float2bfloat16(tile[tx][ty + i * 8]);
}

// ---- K2: merged cast (y=0,1) + ksum (y=2) — homogeneous blocks -----------
__global__ __launch_bounds__(256) void castksum_kernel(
    const float* __restrict__ xq, const float* __restrict__ xk,
    const float* __restrict__ xv, const float* __restrict__ wsum,
    __hip_bfloat16* __restrict__ oq, __hip_bfloat16* __restrict__ ov,
    float* __restrict__ ksum) {
  int y = blockIdx.y;
  if (y < 2) {  // cast: 8 floats/thread, 16B store (R7 known-good)
    const float* src = y ? xv : xq;
    __hip_bfloat16* dst = y ? ov : oq;
    size_t i = (size_t)blockIdx.x * 256 + threadIdx.x;
    const float4* p = (const float4*)src;
    float4 a = p[i * 2], b = p[i * 2 + 1];
    union { __hip_bfloat16 h[8]; bf16x8 v; } u;
    u.h[0] = __float2bfloat16(a.x); u.h[1] = __float2bfloat16(a.y);
    u.h[2] = __float2bfloat16(a.z); u.h[3] = __float2bfloat16(a.w);
    u.h[4] = __float2bfloat16(b.x); u.h[5] = __float2bfloat16(b.y);
    u.h[6] = __float2bfloat16(b.z); u.h[7] = __float2bfloat16(b.w);
    ((bf16x8*)dst)[i] = u.v;
    return;
  }
  if (blockIdx.x >= Mm / 4) return;  // ksum uses 4096 of the 8192 x-blocks
  int row  = blockIdx.x * 4 + (threadIdx.x >> 6);
  int lane = threadIdx.x & 63;
  const float4* rp = (const float4*)(xk + (size_t)row * DIN);
  const float4* wp = (const float4*)wsum;
  float s = 0.f;
#pragma unroll
  for (int i = 0; i < 4; ++i) {
    float4 a = rp[lane + i * 64];
    float4 w = wp[lane + i * 64];
    s += a.x * w.x + a.y * w.y + a.z * w.z + a.w * w.w;
  }
  for (int off = 32; off; off >>= 1) s += __shfl_down(s, off);
  if (lane == 0) ksum[row] = s;
}

// ---- K3: 256x256 8-phase GEMM, persistent x2 over m (B panel L2-hot) -----
// grid 256 = one dispatch round. Block (z,bxp,by) does m-tiles bxp*2+rep,
// rep=0,1 with the SAME B panel (0.5MB, stays in L2 across reps); A panels
// are disjoint per rep -> A read exactly once (R8's failure was sharing A).
// K-loop body = R3/R7-verified schedule (conflicts=0, counted vmcnt(4)).

__device__ __forceinline__ void stage_half(const __hip_bfloat16* g, char* l, int tid) {
#pragma unroll
  for (int j = 0; j < 2; ++j) {
    int c = tid + j * 512;
    int row = c >> 3, ch = c & 7;
    gload16(g + (size_t)row * DIN + ((ch ^ (row & 7)) << 3), l + c * 16);
  }
}

__device__ __forceinline__ bf16x8 lds_frag(const char* base, int row, int kc) {
  return *(const bf16x8*)(base + (((row << 3) + (kc ^ (row & 7))) << 4));
}

#define MFMA_QUAD(MLO, NLO)                                                  \
  _Pragma("unroll") for (int mi = 0; mi < 4; ++mi)                           \
  _Pragma("unroll") for (int ni = 0; ni < 2; ++ni)                           \
  _Pragma("unroll") for (int ks = 0; ks < 2; ++ks)                           \
      acc[(MLO) + mi][(NLO) + ni] = __builtin_amdgcn_mfma_f32_16x16x32_bf16( \
          a[(MLO) + mi][ks], b[(NLO) + ni][ks], acc[(MLO) + mi][(NLO) + ni], 0, 0, 0);

__global__ __launch_bounds__(512, 2) void gemm8_kernel(
    const __hip_bfloat16* __restrict__ Aq, const __hip_bfloat16* __restrict__ Av,
    const __hip_bfloat16* __restrict__ Wt,
    __hip_bfloat16* __restrict__ Qbf, __hip_bfloat16* __restrict__ Vbf) {
  extern __shared__ char lds[];  // [2][A 32KB | B 32KB]

  // XCD swizzle: 256 blocks, chunks of 32/XCD; 4 by-blocks of each bxp land
  // on the same XCD (A-panel L2 reuse x4, as in R7).
  int lin = blockIdx.x;
  int wg  = (lin & 7) * 32 + (lin >> 3);
  int z   = wg >> 7, rem = wg & 127;
  int by  = rem & 3, bxp = rem >> 2;

  const __hip_bfloat16* Ab = z ? Av : Aq;
  const int n0 = by * 256;
  const __hip_bfloat16* Bg = Wt + ((size_t)z * Dd + n0) * DIN;
  __hip_bfloat16* Cc = z ? Vbf : Qbf;

  const int tid = threadIdx.x;
  const int wv = tid >> 6, lane = tid & 63;
  const int wm = (wv >> 2) * 128, wn = (wv & 3) * 64;
  const int fq = lane >> 4, fr = lane & 15;

  // prologue (rep 0)
  {
    const __hip_bfloat16* Ag = Ab + (size_t)(bxp * 2) * 256 * DIN;
    stage_half(Ag,                  lds,                 tid);
    stage_half(Ag + 128 * DIN,      lds + 16384,         tid);
    stage_half(Bg,                  lds + 32768,         tid);
    stage_half(Bg + 128 * DIN,      lds + 49152,         tid);
    stage_half(Ag + 64,             lds + 65536,         tid);
    stage_half(Ag + 128 * DIN + 64, lds + 65536 + 16384, tid);
    asm volatile("s_waitcnt vmcnt(4)" ::: "memory");
    bar();
  }

  for (int rep = 0; rep < 2; ++rep) {
    const int m0 = (bxp * 2 + rep) * 256;
    const __hip_bfloat16* Ag = Ab + (size_t)m0 * DIN;
    f32x4 acc[8][4] = {};

    for (int t = 0; t < NT; ++t) {
      char* buf  = lds + (t & 1) * 65536;
      char* bufN = lds + ((t + 1) & 1) * 65536;
      const char* At = buf;
      const char* Bt = buf + 32768;
      bf16x8 a[8][2], b[4][2];

      // ---- P0: read a[0..3], b[0..1]; stage B(t+1)h0
#pragma unroll
      for (int mi = 0; mi < 4; ++mi)
#pragma unroll
        for (int ks = 0; ks < 2; ++ks)
          a[mi][ks] = lds_frag(At, wm + mi * 16 + fr, ks * 4 + fq);
#pragma unroll
      for (int ni = 0; ni < 2; ++ni)
#pragma unroll
        for (int ks = 0; ks < 2; ++ks)
          b[ni][ks] = lds_frag(Bt, wn + ni * 16 + fr, ks * 4 + fq);
      if (t + 1 < NT) stage_half(Bg + (size_t)(t + 1) * 64, bufN + 32768, tid);
      bar();
      __builtin_amdgcn_s_setprio(1);
      MFMA_QUAD(0, 0);
      __builtin_amdgcn_s_setprio(0);
      bar();

      // ---- P1: read a[4..7]; stage B(t+1)h1
#pragma unroll
      for (int mi = 4; mi < 8; ++mi)
#pragma unroll
        for (int ks = 0; ks < 2; ++ks)
          a[mi][ks] = lds_frag(At, wm + mi * 16 + fr, ks * 4 + fq);
      if (t + 1 < NT)
        stage_half(Bg + 128 * DIN + (size_t)(t + 1) * 64, bufN + 49152, tid);
      bar();
      __builtin_amdgcn_s_setprio(1);
      MFMA_QUAD(4, 0);
      __builtin_amdgcn_s_setprio(0);
      bar();

      // ---- P2: read b[2..3]; stage A(t+2)h0 into buf (A dead after P1)
#pragma unroll
      for (int ni = 2; ni < 4; ++ni)
#pragma unroll
        for (int ks = 0; ks < 2; ++ks)
          b[ni][ks] = lds_frag(Bt, wn + ni * 16 + fr, ks * 4 + fq);
      if (t + 2 < NT) stage_half(Ag + (size_t)(t + 2) * 64, buf, tid);
      bar();
      __builtin_amdgcn_s_setprio(1);
      MFMA_QUAD(0, 2);
      __builtin_amdgcn_s_setprio(0);
      bar();

      // ---- P3: stage A(t+2)h1; counted vmcnt once per tile (T4)
      if (t + 2 < NT)
        stage_half(Ag + 128 * DIN + (size_t)(t + 2) * 64, buf + 16384, tid);
      if (t + 1 < NT) {
        if (t + 2 < NT) asm volatile("s_waitcnt vmcnt(4)" ::: "memory");
        else            asm volatile("s_waitcnt vmcnt(0)" ::: "memory");
      }
      bar();
      __builtin_amdgcn_s_setprio(1);
      MFMA_QUAD(4, 2);
      __builtin_amdgcn_s_setprio(0);
      bar();
    }

    // epilogue: C/D layout col=lane&15, row=(lane>>4)*4+reg
#pragma unroll
    for (int mi = 0; mi < 8; ++mi) {
#pragma unroll
      for (int ni = 0; ni < 4; ++ni) {
        f32x4 v = acc[mi][ni];
        int row = m0 + wm + mi * 16 + fq * 4;
        int col = n0 + wn + ni * 16 + fr;
#pragma unroll
        for (int j = 0; j < 4; ++j)
          Cc[(size_t)(row + j) * Dd + col] = __float2bfloat16(v[j]);
      }
    }

    // rep-1 prologue: fresh A panel (disjoint rows), same B panel (L2-hot)
    if (rep == 0) {
      const __hip_bfloat16* Ag1 = Ab + (size_t)(m0 + 256) * DIN;
      stage_half(Ag1,                  lds,                 tid);
      stage_half(Ag1 + 128 * DIN,      lds + 16384,         tid);
      stage_half(Bg,                   lds + 32768,         tid);
      stage_half(Bg + 128 * DIN,       lds + 49152,         tid);
      stage_half(Ag1 + 64,             lds + 65536,         tid);
      stage_half(Ag1 + 128 * DIN + 64, lds + 65536 + 16384, tid);
      asm volatile("s_waitcnt vmcnt(4)" ::: "memory");
      bar();
    }
  }
}

// ---- K5: per-chunk local scan end values E[b][c][d] (R7 known-good) ------
__global__ void scanA_kernel(const __hip_bfloat16* __restrict__ Vbf,
                             const float* __restrict__ ksum,
                             float* __restrict__ E) {
  int b = blockIdx.x, c = blockIdx.y;
  int d = blockIdx.z * 256 + threadIdx.x;
  const __hip_bfloat16* Vp = Vbf + ((size_t)(b * Tt + c * CL) * Dd) + d;
  const float* kp = ksum + b * Tt + c * CL;
  float s = 0.f;
#pragma unroll 8
  for (int t = 0; t < CL; ++t) {
    float u = kp[t] * __bfloat162float(Vp[(size_t)t * Dd]);
    if (c == 0 && t == 0) u = 0.f;
    s = s * GAMMA + u;
  }
  E[((size_t)b * NC + c) * Dd + d] = s;
}

// ---- K6: compose carries across chunks (R7 known-good) -------------------
__global__ void scanB_kernel(const float* __restrict__ E, float* __restrict__ carry,
                             float gCL) {
  int b = blockIdx.x;
  int d = blockIdx.y * 256 + threadIdx.x;
  float send = 0.f;
  for (int c = 0; c < NC; ++c) {
    size_t idx = ((size_t)b * NC + c) * Dd + d;
    float e = E[idx];
    carry[idx] = send;          // S at end of chunk c-1
    send = e + gCL * send;
  }
}

// ---- K7: final scan with carry, out = Q * S (R7 known-good) --------------
__global__ void final_kernel(const __hip_bfloat16* __restrict__ Vbf,
                             const __hip_bfloat16* __restrict__ Qbf,
                             const float* __restrict__ ksum,
                             const float* __restrict__ carry,
                             float* __restrict__ outp) {
  int b = blockIdx.x, c = blockIdx.y;
  int d = blockIdx.z * 256 + threadIdx.x;
  size_t base = ((size_t)(b * Tt + c * CL) * Dd) + d;
  float s = carry[((size_t)b * NC + c) * Dd + d];
  const float* kp = ksum + b * Tt + c * CL;
#pragma unroll 4
  for (int t = 0; t < CL; ++t) {
    float u = kp[t] * __bfloat162float(Vbf[base + (size_t)t * Dd]);
    if (c == 0 && t == 0) u = 0.f;
    s = s * GAMMA + u;
    outp[base + (size_t)t * Dd] = __bfloat162float(Qbf[base + (size_t)t * Dd]) * s;
  }
}

extern "C" void kernel_launch(void* const* d_in, const int* in_sizes, int n_in,
                              void* d_out, int out_size, void* d_ws, size_t ws_size,
                              hipStream_t stream) {
  (void)in_sizes; (void)n_in; (void)out_size; (void)ws_size;
  const float* xq = (const float*)d_in[0];
  const float* xk = (const float*)d_in[1];
  const float* xv = (const float*)d_in[2];
  const float* Wq = (const float*)d_in[3];
  const float* Wk = (const float*)d_in[4];
  const float* Wv = (const float*)d_in[5];
  float* outp = (float*)d_out;

  char* ws = (char*)d_ws;
  size_t off = 0;
  auto alloc = [&](size_t bytes) {
    char* p = ws + off;
    off += (bytes + 255) & ~(size_t)255;
    return p;
  };
  __hip_bfloat16* xq_bf = (__hip_bfloat16*)alloc((size_t)Mm * DIN * 2);
  __hip_bfloat16* xv_bf = (__hip_bfloat16*)alloc((size_t)Mm * DIN * 2);
  __hip_bfloat16* Wt    = (__hip_bfloat16*)alloc((size_t)2 * DIN * Dd * 2);
  __hip_bfloat16* Qbf   = (__hip_bfloat16*)alloc((size_t)Mm * Dd * 2);
  __hip_bfloat16* Vbf   = (__hip_bfloat16*)alloc((size_t)Mm * Dd * 2);
  float* wsum  = (float*)alloc((size_t)DIN * 4);
  float* ksum  = (float*)alloc((size_t)Mm * 4);
  float* E     = (float*)alloc((size_t)Bb * NC * Dd * 4);
  float* carry = (float*)alloc((size_t)Bb * NC * Dd * 4);

  double g = 1.0;
  for (int i = 0; i < CL; ++i) g *= (double)GAMMA;
  float gCL = (float)g;

  (void)hipFuncSetAttribute((const void*)gemm8_kernel,
                            hipFuncAttributeMaxDynamicSharedMemorySize, 131072);

  prep_kernel<<<256 + 2048, 256, 0, stream>>>(Wq, Wk, Wv, wsum, Wt);
  castksum_kernel<<<dim3(Mm * DIN / 8 / 256, 3), 256, 0, stream>>>(
      xq, xk, xv, wsum, xq_bf, xv_bf, ksum);
  gemm8_kernel<<<256, 512, 131072, stream>>>(xq_bf, xv_bf, Wt, Qbf, Vbf);
  scanA_kernel<<<dim3(Bb, NC, Dd / 256), 256, 0, stream>>>(Vbf, ksum, E);
  scanB_kernel<<<dim3(Bb, Dd / 256), 256, 0, stream>>>(E, carry, gCL);
  final_kernel<<<dim3(Bb, NC, Dd / 256), 256, 0, stream>>>(Vbf, Qbf, ksum, carry, outp);
}

// Round 11
// 151.530 us; speedup vs baseline: 1.5576x; 1.1430x over previous
//
#include <hip/hip_runtime.h>
#include <hip/hip_bf16.h>

#define GAMMA 0.9865f

typedef __attribute__((ext_vector_type(8))) short bf16x8;
typedef __attribute__((ext_vector_type(4))) float f32x4;

static constexpr int Bb  = 8;
static constexpr int Tt  = 2048;
static constexpr int DIN = 1024;
static constexpr int Dd  = 1024;
static constexpr int Mm  = Bb * Tt;      // 16384
static constexpr int CL  = 64;           // chunk length for scan
static constexpr int NC  = Tt / CL;      // 32 chunks
static constexpr int NT  = DIN / 64;     // 16 K-tiles of BK=64

__device__ __forceinline__ void gload16(const void* g, void* l) {
  __builtin_amdgcn_global_load_lds(
      (const __attribute__((address_space(1))) void*)g,
      (__attribute__((address_space(3))) void*)l, 16, 0, 0);
}

__device__ __forceinline__ void bar() {
  asm volatile("" ::: "memory");
  __builtin_amdgcn_s_barrier();
  asm volatile("" ::: "memory");
}

// ---- K1: merged prep: wsum (blocks 0..255) + Wt transpose (256..2303) ----
__global__ __launch_bounds__(256) void prep_kernel(
    const float* __restrict__ Wq, const float* __restrict__ Wk,
    const float* __restrict__ Wv, float* __restrict__ wsum,
    __hip_bfloat16* __restrict__ Wt) {
  int bid = blockIdx.x;
  if (bid < 256) {
    int row  = bid * 4 + (threadIdx.x >> 6);
    int lane = threadIdx.x & 63;
    const float4* rp = (const float4*)(Wk + (size_t)row * DIN);
    float s = 0.f;
#pragma unroll
    for (int i = 0; i < 4; ++i) {
      float4 v = rp[lane + i * 64];
      s += v.x + v.y + v.z + v.w;
    }
    for (int off = 32; off; off >>= 1) s += __shfl_down(s, off);
    if (lane == 0) wsum[row] = s;
    return;
  }
  int wid = bid - 256;
  int z = wid >> 10, rem = wid & 1023;
  int kb = rem & 31, nb = rem >> 5;
  const float* W = z ? Wv : Wq;
  __hip_bfloat16* outp = Wt + (size_t)z * DIN * Dd;
  __shared__ float tile[32][33];
  int k0 = kb * 32, n0 = nb * 32;
  int tx = threadIdx.x & 31, ty = threadIdx.x >> 5;
#pragma unroll
  for (int i = 0; i < 4; ++i)
    tile[ty + i * 8][tx] = W[(size_t)(k0 + ty + i * 8) * Dd + n0 + tx];
  __syncthreads();
#pragma unroll
  for (int i = 0; i < 4; ++i)
    outp[(size_t)(n0 + ty + i * 8) * DIN + k0 + tx] =
        __float2bfloat16(tile[tx][ty + i * 8]);
}

// ---- K2: merged cast (y=0,1) + ksum (y=2) — homogeneous blocks -----------
__global__ __launch_bounds__(256) void castksum_kernel(
    const float* __restrict__ xq, const float* __restrict__ xk,
    const float* __restrict__ xv, const float* __restrict__ wsum,
    __hip_bfloat16* __restrict__ oq, __hip_bfloat16* __restrict__ ov,
    float* __restrict__ ksum) {
  int y = blockIdx.y;
  if (y < 2) {  // cast: 8 floats/thread, 16B store (R7 known-good)
    const float* src = y ? xv : xq;
    __hip_bfloat16* dst = y ? ov : oq;
    size_t i = (size_t)blockIdx.x * 256 + threadIdx.x;
    const float4* p = (const float4*)src;
    float4 a = p[i * 2], b = p[i * 2 + 1];
    union { __hip_bfloat16 h[8]; bf16x8 v; } u;
    u.h[0] = __float2bfloat16(a.x); u.h[1] = __float2bfloat16(a.y);
    u.h[2] = __float2bfloat16(a.z); u.h[3] = __float2bfloat16(a.w);
    u.h[4] = __float2bfloat16(b.x); u.h[5] = __float2bfloat16(b.y);
    u.h[6] = __float2bfloat16(b.z); u.h[7] = __float2bfloat16(b.w);
    ((bf16x8*)dst)[i] = u.v;
    return;
  }
  if (blockIdx.x >= Mm / 4) return;  // ksum uses 4096 of the 8192 x-blocks
  int row  = blockIdx.x * 4 + (threadIdx.x >> 6);
  int lane = threadIdx.x & 63;
  const float4* rp = (const float4*)(xk + (size_t)row * DIN);
  const float4* wp = (const float4*)wsum;
  float s = 0.f;
#pragma unroll
  for (int i = 0; i < 4; ++i) {
    float4 a = rp[lane + i * 64];
    float4 w = wp[lane + i * 64];
    s += a.x * w.x + a.y * w.y + a.z * w.z + a.w * w.w;
  }
  for (int off = 32; off; off >>= 1) s += __shfl_down(s, off);
  if (lane == 0) ksum[row] = s;
}

// ---- K3: 256x256 8-phase bf16 MFMA GEMM (T2+T3+T4+T5) — R7 known-good ----
// 512 blocks, one 256x256 tile each (best measured: 73.7us, conflicts=0).
// Persistent x2 variants refuted: R8 (shared A -> +41MB refetch), R10
// (shared B -> +28MB write amplification from staggered partial-line evicts).
__device__ __forceinline__ void stage_half(const __hip_bfloat16* g, char* l, int tid) {
#pragma unroll
  for (int j = 0; j < 2; ++j) {
    int c = tid + j * 512;
    int row = c >> 3, ch = c & 7;
    gload16(g + (size_t)row * DIN + ((ch ^ (row & 7)) << 3), l + c * 16);
  }
}

__device__ __forceinline__ bf16x8 lds_frag(const char* base, int row, int kc) {
  return *(const bf16x8*)(base + (((row << 3) + (kc ^ (row & 7))) << 4));
}

#define MFMA_QUAD(MLO, NLO)                                                  \
  _Pragma("unroll") for (int mi = 0; mi < 4; ++mi)                           \
  _Pragma("unroll") for (int ni = 0; ni < 2; ++ni)                           \
  _Pragma("unroll") for (int ks = 0; ks < 2; ++ks)                           \
      acc[(MLO) + mi][(NLO) + ni] = __builtin_amdgcn_mfma_f32_16x16x32_bf16( \
          a[(MLO) + mi][ks], b[(NLO) + ni][ks], acc[(MLO) + mi][(NLO) + ni], 0, 0, 0);

__global__ __launch_bounds__(512, 2) void gemm8_kernel(
    const __hip_bfloat16* __restrict__ Aq, const __hip_bfloat16* __restrict__ Av,
    const __hip_bfloat16* __restrict__ Wt,
    __hip_bfloat16* __restrict__ Qbf, __hip_bfloat16* __restrict__ Vbf) {
  extern __shared__ char lds[];  // [2][A 32KB | B 32KB]

  // XCD-bijective swizzle: 512 blocks, 512 % 8 == 0
  int lin = blockIdx.x;
  int wg  = (lin & 7) * 64 + (lin >> 3);
  int z   = wg >> 8, rem = wg & 255;
  int by  = rem & 3, bx = rem >> 2;

  const __hip_bfloat16* Ab = z ? Av : Aq;
  const int m0 = bx * 256, n0 = by * 256;
  const __hip_bfloat16* Ag = Ab + (size_t)m0 * DIN;
  const __hip_bfloat16* Bg = Wt + ((size_t)z * Dd + n0) * DIN;
  __hip_bfloat16* Cc = z ? Vbf : Qbf;

  const int tid = threadIdx.x;
  const int wv = tid >> 6, lane = tid & 63;
  const int wm = (wv >> 2) * 128, wn = (wv & 3) * 64;
  const int fq = lane >> 4, fr = lane & 15;

  f32x4 acc[8][4] = {};

  // prologue: tile0 (A+B), tile1 (A only; its B staged during tile0 phases)
  stage_half(Ag,                  lds,                 tid);
  stage_half(Ag + 128 * DIN,      lds + 16384,         tid);
  stage_half(Bg,                  lds + 32768,         tid);
  stage_half(Bg + 128 * DIN,      lds + 49152,         tid);
  stage_half(Ag + 64,             lds + 65536,         tid);
  stage_half(Ag + 128 * DIN + 64, lds + 65536 + 16384, tid);
  asm volatile("s_waitcnt vmcnt(4)" ::: "memory");
  bar();

  for (int t = 0; t < NT; ++t) {
    char* buf  = lds + (t & 1) * 65536;
    char* bufN = lds + ((t + 1) & 1) * 65536;
    const char* At = buf;
    const char* Bt = buf + 32768;
    bf16x8 a[8][2], b[4][2];

    // ---- P0: read a[0..3], b[0..1]; stage B(t+1)h0
#pragma unroll
    for (int mi = 0; mi < 4; ++mi)
#pragma unroll
      for (int ks = 0; ks < 2; ++ks)
        a[mi][ks] = lds_frag(At, wm + mi * 16 + fr, ks * 4 + fq);
#pragma unroll
    for (int ni = 0; ni < 2; ++ni)
#pragma unroll
      for (int ks = 0; ks < 2; ++ks)
        b[ni][ks] = lds_frag(Bt, wn + ni * 16 + fr, ks * 4 + fq);
    if (t + 1 < NT) stage_half(Bg + (size_t)(t + 1) * 64, bufN + 32768, tid);
    bar();
    __builtin_amdgcn_s_setprio(1);
    MFMA_QUAD(0, 0);
    __builtin_amdgcn_s_setprio(0);
    bar();

    // ---- P1: read a[4..7]; stage B(t+1)h1
#pragma unroll
    for (int mi = 4; mi < 8; ++mi)
#pragma unroll
      for (int ks = 0; ks < 2; ++ks)
        a[mi][ks] = lds_frag(At, wm + mi * 16 + fr, ks * 4 + fq);
    if (t + 1 < NT)
      stage_half(Bg + 128 * DIN + (size_t)(t + 1) * 64, bufN + 49152, tid);
    bar();
    __builtin_amdgcn_s_setprio(1);
    MFMA_QUAD(4, 0);
    __builtin_amdgcn_s_setprio(0);
    bar();

    // ---- P2: read b[2..3]; stage A(t+2)h0 into buf (A dead after P1)
#pragma unroll
    for (int ni = 2; ni < 4; ++ni)
#pragma unroll
      for (int ks = 0; ks < 2; ++ks)
        b[ni][ks] = lds_frag(Bt, wn + ni * 16 + fr, ks * 4 + fq);
    if (t + 2 < NT) stage_half(Ag + (size_t)(t + 2) * 64, buf, tid);
    bar();
    __builtin_amdgcn_s_setprio(1);
    MFMA_QUAD(0, 2);
    __builtin_amdgcn_s_setprio(0);
    bar();

    // ---- P3: stage A(t+2)h1; counted vmcnt once per tile (T4)
    if (t + 2 < NT)
      stage_half(Ag + 128 * DIN + (size_t)(t + 2) * 64, buf + 16384, tid);
    if (t + 1 < NT) {
      if (t + 2 < NT) asm volatile("s_waitcnt vmcnt(4)" ::: "memory");
      else            asm volatile("s_waitcnt vmcnt(0)" ::: "memory");
    }
    bar();
    __builtin_amdgcn_s_setprio(1);
    MFMA_QUAD(4, 2);
    __builtin_amdgcn_s_setprio(0);
    bar();
  }

  // epilogue: C/D layout col=lane&15, row=(lane>>4)*4+reg
#pragma unroll
  for (int mi = 0; mi < 8; ++mi) {
#pragma unroll
    for (int ni = 0; ni < 4; ++ni) {
      f32x4 v = acc[mi][ni];
      int row = m0 + wm + mi * 16 + fq * 4;
      int col = n0 + wn + ni * 16 + fr;
#pragma unroll
      for (int j = 0; j < 4; ++j)
        Cc[(size_t)(row + j) * Dd + col] = __float2bfloat16(v[j]);
    }
  }
}

// ---- K5: per-chunk local scan end values E[b][c][d] (R7 known-good) ------
__global__ void scanA_kernel(const __hip_bfloat16* __restrict__ Vbf,
                             const float* __restrict__ ksum,
                             float* __restrict__ E) {
  int b = blockIdx.x, c = blockIdx.y;
  int d = blockIdx.z * 256 + threadIdx.x;
  const __hip_bfloat16* Vp = Vbf + ((size_t)(b * Tt + c * CL) * Dd) + d;
  const float* kp = ksum + b * Tt + c * CL;
  float s = 0.f;
#pragma unroll 8
  for (int t = 0; t < CL; ++t) {
    float u = kp[t] * __bfloat162float(Vp[(size_t)t * Dd]);
    if (c == 0 && t == 0) u = 0.f;
    s = s * GAMMA + u;
  }
  E[((size_t)b * NC + c) * Dd + d] = s;
}

// ---- K6: compose carries across chunks (R7 known-good) -------------------
__global__ void scanB_kernel(const float* __restrict__ E, float* __restrict__ carry,
                             float gCL) {
  int b = blockIdx.x;
  int d = blockIdx.y * 256 + threadIdx.x;
  float send = 0.f;
  for (int c = 0; c < NC; ++c) {
    size_t idx = ((size_t)b * NC + c) * Dd + d;
    float e = E[idx];
    carry[idx] = send;          // S at end of chunk c-1
    send = e + gCL * send;
  }
}

// ---- K7: final scan with carry, out = Q * S (R7 known-good) --------------
__global__ void final_kernel(const __hip_bfloat16* __restrict__ Vbf,
                             const __hip_bfloat16* __restrict__ Qbf,
                             const float* __restrict__ ksum,
                             const float* __restrict__ carry,
                             float* __restrict__ outp) {
  int b = blockIdx.x, c = blockIdx.y;
  int d = blockIdx.z * 256 + threadIdx.x;
  size_t base = ((size_t)(b * Tt + c * CL) * Dd) + d;
  float s = carry[((size_t)b * NC + c) * Dd + d];
  const float* kp = ksum + b * Tt + c * CL;
#pragma unroll 4
  for (int t = 0; t < CL; ++t) {
    float u = kp[t] * __bfloat162float(Vbf[base + (size_t)t * Dd]);
    if (c == 0 && t == 0) u = 0.f;
    s = s * GAMMA + u;
    outp[base + (size_t)t * Dd] = __bfloat162float(Qbf[base + (size_t)t * Dd]) * s;
  }
}

extern "C" void kernel_launch(void* const* d_in, const int* in_sizes, int n_in,
                              void* d_out, int out_size, void* d_ws, size_t ws_size,
                              hipStream_t stream) {
  (void)in_sizes; (void)n_in; (void)out_size; (void)ws_size;
  const float* xq = (const float*)d_in[0];
  const float* xk = (const float*)d_in[1];
  const float* xv = (const float*)d_in[2];
  const float* Wq = (const float*)d_in[3];
  const float* Wk = (const float*)d_in[4];
  const float* Wv = (const float*)d_in[5];
  float* outp = (float*)d_out;

  char* ws = (char*)d_ws;
  size_t off = 0;
  auto alloc = [&](size_t bytes) {
    char* p = ws + off;
    off += (bytes + 255) & ~(size_t)255;
    return p;
  };
  __hip_bfloat16* xq_bf = (__hip_bfloat16*)alloc((size_t)Mm * DIN * 2);
  __hip_bfloat16* xv_bf = (__hip_bfloat16*)alloc((size_t)Mm * DIN * 2);
  __hip_bfloat16* Wt    = (__hip_bfloat16*)alloc((size_t)2 * DIN * Dd * 2);
  __hip_bfloat16* Qbf   = (__hip_bfloat16*)alloc((size_t)Mm * Dd * 2);
  __hip_bfloat16* Vbf   = (__hip_bfloat16*)alloc((size_t)Mm * Dd * 2);
  float* wsum  = (float*)alloc((size_t)DIN * 4);
  float* ksum  = (float*)alloc((size_t)Mm * 4);
  float* E     = (float*)alloc((size_t)Bb * NC * Dd * 4);
  float* carry = (float*)alloc((size_t)Bb * NC * Dd * 4);

  double g = 1.0;
  for (int i = 0; i < CL; ++i) g *= (double)GAMMA;
  float gCL = (float)g;

  (void)hipFuncSetAttribute((const void*)gemm8_kernel,
                            hipFuncAttributeMaxDynamicSharedMemorySize, 131072);

  prep_kernel<<<256 + 2048, 256, 0, stream>>>(Wq, Wk, Wv, wsum, Wt);
  castksum_kernel<<<dim3(Mm * DIN / 8 / 256, 3), 256, 0, stream>>>(
      xq, xk, xv, wsum, xq_bf, xv_bf, ksum);
  gemm8_kernel<<<512, 512, 131072, stream>>>(xq_bf, xv_bf, Wt, Qbf, Vbf);
  scanA_kernel<<<dim3(Bb, NC, Dd / 256), 256, 0, stream>>>(Vbf, ksum, E);
  scanB_kernel<<<dim3(Bb, Dd / 256), 256, 0, stream>>>(E, carry, gCL);
  final_kernel<<<dim3(Bb, NC, Dd / 256), 256, 0, stream>>>(Vbf, Qbf, ksum, carry, outp);
}

// Round 12
// 147.294 us; speedup vs baseline: 1.6024x; 1.0288x over previous
//
#include <hip/hip_runtime.h>
#include <hip/hip_bf16.h>

#define GAMMA 0.9865f

typedef __attribute__((ext_vector_type(8))) short bf16x8;
typedef __attribute__((ext_vector_type(4))) float f32x4;

static constexpr int Bb  = 8;
static constexpr int Tt  = 2048;
static constexpr int DIN = 1024;
static constexpr int Dd  = 1024;
static constexpr int Mm  = Bb * Tt;      // 16384
static constexpr int CL  = 64;           // chunk length for scan
static constexpr int NC  = Tt / CL;      // 32 chunks
static constexpr int NT  = DIN / 64;     // 16 K-tiles of BK=64

__device__ __forceinline__ void gload16(const void* g, void* l) {
  __builtin_amdgcn_global_load_lds(
      (const __attribute__((address_space(1))) void*)g,
      (__attribute__((address_space(3))) void*)l, 16, 0, 0);
}

__device__ __forceinline__ void bar() {
  asm volatile("" ::: "memory");
  __builtin_amdgcn_s_barrier();
  asm volatile("" ::: "memory");
}

__device__ __forceinline__ float bf16_to_f32(unsigned short u) {
  return __uint_as_float(((unsigned int)u) << 16);
}

// ---- K1: merged prep: wsum (blocks 0..255) + Wt transpose (256..2303) ----
__global__ __launch_bounds__(256) void prep_kernel(
    const float* __restrict__ Wq, const float* __restrict__ Wk,
    const float* __restrict__ Wv, float* __restrict__ wsum,
    __hip_bfloat16* __restrict__ Wt) {
  int bid = blockIdx.x;
  if (bid < 256) {
    int row  = bid * 4 + (threadIdx.x >> 6);
    int lane = threadIdx.x & 63;
    const float4* rp = (const float4*)(Wk + (size_t)row * DIN);
    float s = 0.f;
#pragma unroll
    for (int i = 0; i < 4; ++i) {
      float4 v = rp[lane + i * 64];
      s += v.x + v.y + v.z + v.w;
    }
    for (int off = 32; off; off >>= 1) s += __shfl_down(s, off);
    if (lane == 0) wsum[row] = s;
    return;
  }
  int wid = bid - 256;
  int z = wid >> 10, rem = wid & 1023;
  int kb = rem & 31, nb = rem >> 5;
  const float* W = z ? Wv : Wq;
  __hip_bfloat16* outp = Wt + (size_t)z * DIN * Dd;
  __shared__ float tile[32][33];
  int k0 = kb * 32, n0 = nb * 32;
  int tx = threadIdx.x & 31, ty = threadIdx.x >> 5;
#pragma unroll
  for (int i = 0; i < 4; ++i)
    tile[ty + i * 8][tx] = W[(size_t)(k0 + ty + i * 8) * Dd + n0 + tx];
  __syncthreads();
#pragma unroll
  for (int i = 0; i < 4; ++i)
    outp[(size_t)(n0 + ty + i * 8) * DIN + k0 + tx] =
        __float2bfloat16(tile[tx][ty + i * 8]);
}

// ---- K2: merged cast (y=0,1) + ksum (y=2) — homogeneous blocks -----------
__global__ __launch_bounds__(256) void castksum_kernel(
    const float* __restrict__ xq, const float* __restrict__ xk,
    const float* __restrict__ xv, const float* __restrict__ wsum,
    __hip_bfloat16* __restrict__ oq, __hip_bfloat16* __restrict__ ov,
    float* __restrict__ ksum) {
  int y = blockIdx.y;
  if (y < 2) {
    const float* src = y ? xv : xq;
    __hip_bfloat16* dst = y ? ov : oq;
    size_t i = (size_t)blockIdx.x * 256 + threadIdx.x;
    const float4* p = (const float4*)src;
    float4 a = p[i * 2], b = p[i * 2 + 1];
    union { __hip_bfloat16 h[8]; bf16x8 v; } u;
    u.h[0] = __float2bfloat16(a.x); u.h[1] = __float2bfloat16(a.y);
    u.h[2] = __float2bfloat16(a.z); u.h[3] = __float2bfloat16(a.w);
    u.h[4] = __float2bfloat16(b.x); u.h[5] = __float2bfloat16(b.y);
    u.h[6] = __float2bfloat16(b.z); u.h[7] = __float2bfloat16(b.w);
    ((bf16x8*)dst)[i] = u.v;
    return;
  }
  if (blockIdx.x >= Mm / 4) return;
  int row  = blockIdx.x * 4 + (threadIdx.x >> 6);
  int lane = threadIdx.x & 63;
  const float4* rp = (const float4*)(xk + (size_t)row * DIN);
  const float4* wp = (const float4*)wsum;
  float s = 0.f;
#pragma unroll
  for (int i = 0; i < 4; ++i) {
    float4 a = rp[lane + i * 64];
    float4 w = wp[lane + i * 64];
    s += a.x * w.x + a.y * w.y + a.z * w.z + a.w * w.w;
  }
  for (int off = 32; off; off >>= 1) s += __shfl_down(s, off);
  if (lane == 0) ksum[row] = s;
}

// ---- GEMM core: R7-verified 8-phase K-loop (conflicts=0, vmcnt(4)/tile) --
__device__ __forceinline__ void stage_half(const __hip_bfloat16* g, char* l, int tid) {
#pragma unroll
  for (int j = 0; j < 2; ++j) {
    int c = tid + j * 512;
    int row = c >> 3, ch = c & 7;
    gload16(g + (size_t)row * DIN + ((ch ^ (row & 7)) << 3), l + c * 16);
  }
}

__device__ __forceinline__ bf16x8 lds_frag(const char* base, int row, int kc) {
  return *(const bf16x8*)(base + (((row << 3) + (kc ^ (row & 7))) << 4));
}

#define MFMA_QUAD(MLO, NLO)                                                  \
  _Pragma("unroll") for (int mi = 0; mi < 4; ++mi)                           \
  _Pragma("unroll") for (int ni = 0; ni < 2; ++ni)                           \
  _Pragma("unroll") for (int ks = 0; ks < 2; ++ks)                           \
      acc[(MLO) + mi][(NLO) + ni] = __builtin_amdgcn_mfma_f32_16x16x32_bf16( \
          a[(MLO) + mi][ks], b[(NLO) + ni][ks], acc[(MLO) + mi][(NLO) + ni], 0, 0, 0);

__device__ __forceinline__ void gemm_core(const __hip_bfloat16* Ag,
                                          const __hip_bfloat16* Bg, char* lds,
                                          int tid, int wm, int wn, int fq, int fr,
                                          f32x4 (&acc)[8][4]) {
  stage_half(Ag,                  lds,                 tid);
  stage_half(Ag + 128 * DIN,      lds + 16384,         tid);
  stage_half(Bg,                  lds + 32768,         tid);
  stage_half(Bg + 128 * DIN,      lds + 49152,         tid);
  stage_half(Ag + 64,             lds + 65536,         tid);
  stage_half(Ag + 128 * DIN + 64, lds + 65536 + 16384, tid);
  asm volatile("s_waitcnt vmcnt(4)" ::: "memory");
  bar();

  for (int t = 0; t < NT; ++t) {
    char* buf  = lds + (t & 1) * 65536;
    char* bufN = lds + ((t + 1) & 1) * 65536;
    const char* At = buf;
    const char* Bt = buf + 32768;
    bf16x8 a[8][2], b[4][2];

#pragma unroll
    for (int mi = 0; mi < 4; ++mi)
#pragma unroll
      for (int ks = 0; ks < 2; ++ks)
        a[mi][ks] = lds_frag(At, wm + mi * 16 + fr, ks * 4 + fq);
#pragma unroll
    for (int ni = 0; ni < 2; ++ni)
#pragma unroll
      for (int ks = 0; ks < 2; ++ks)
        b[ni][ks] = lds_frag(Bt, wn + ni * 16 + fr, ks * 4 + fq);
    if (t + 1 < NT) stage_half(Bg + (size_t)(t + 1) * 64, bufN + 32768, tid);
    bar();
    __builtin_amdgcn_s_setprio(1);
    MFMA_QUAD(0, 0);
    __builtin_amdgcn_s_setprio(0);
    bar();

#pragma unroll
    for (int mi = 4; mi < 8; ++mi)
#pragma unroll
      for (int ks = 0; ks < 2; ++ks)
        a[mi][ks] = lds_frag(At, wm + mi * 16 + fr, ks * 4 + fq);
    if (t + 1 < NT)
      stage_half(Bg + 128 * DIN + (size_t)(t + 1) * 64, bufN + 49152, tid);
    bar();
    __builtin_amdgcn_s_setprio(1);
    MFMA_QUAD(4, 0);
    __builtin_amdgcn_s_setprio(0);
    bar();

#pragma unroll
    for (int ni = 2; ni < 4; ++ni)
#pragma unroll
      for (int ks = 0; ks < 2; ++ks)
        b[ni][ks] = lds_frag(Bt, wn + ni * 16 + fr, ks * 4 + fq);
    if (t + 2 < NT) stage_half(Ag + (size_t)(t + 2) * 64, buf, tid);
    bar();
    __builtin_amdgcn_s_setprio(1);
    MFMA_QUAD(0, 2);
    __builtin_amdgcn_s_setprio(0);
    bar();

    if (t + 2 < NT)
      stage_half(Ag + 128 * DIN + (size_t)(t + 2) * 64, buf + 16384, tid);
    if (t + 1 < NT) {
      if (t + 2 < NT) asm volatile("s_waitcnt vmcnt(4)" ::: "memory");
      else            asm volatile("s_waitcnt vmcnt(0)" ::: "memory");
    }
    bar();
    __builtin_amdgcn_s_setprio(1);
    MFMA_QUAD(4, 2);
    __builtin_amdgcn_s_setprio(0);
    bar();
  }
}

// ---- K3a: V = xv_bf x WvT — standard bf16 epilogue (grid 256) ------------
__global__ __launch_bounds__(512, 2) void gemmV_kernel(
    const __hip_bfloat16* __restrict__ Av, const __hip_bfloat16* __restrict__ Wt,
    __hip_bfloat16* __restrict__ Vbf) {
  extern __shared__ char lds[];
  int lin = blockIdx.x;
  int wg  = (lin & 7) * 32 + (lin >> 3);   // 256 blocks, bijective (256%8==0)
  int by  = wg & 3, bx = wg >> 2;
  const int m0 = bx * 256, n0 = by * 256;
  const __hip_bfloat16* Ag = Av + (size_t)m0 * DIN;
  const __hip_bfloat16* Bg = Wt + ((size_t)Dd + n0) * DIN;  // Wv half

  const int tid = threadIdx.x;
  const int wv = tid >> 6, lane = tid & 63;
  const int wm = (wv >> 2) * 128, wn = (wv & 3) * 64;
  const int fq = lane >> 4, fr = lane & 15;

  f32x4 acc[8][4] = {};
  gemm_core(Ag, Bg, lds, tid, wm, wn, fq, fr, acc);

#pragma unroll
  for (int mi = 0; mi < 8; ++mi) {
#pragma unroll
    for (int ni = 0; ni < 4; ++ni) {
      f32x4 v = acc[mi][ni];
      int row = m0 + wm + mi * 16 + fq * 4;
      int col = n0 + wn + ni * 16 + fr;
#pragma unroll
      for (int j = 0; j < 4; ++j)
        Vbf[(size_t)(row + j) * Dd + col] = __float2bfloat16(v[j]);
    }
  }
}

// ---- K3b: Q GEMM with fused scan+final epilogue (grid 256) ---------------
// After K-loop: stage the matching 256x256 V-tile into LDS (128KB, swizzled
// source / linear dest, rule #21), recompute S in-tile from carry+ksum
// (fp32 scan, S stored bf16 in place), then out = accQ * S (fp32 stores).
// LDS elem (t,col) lives at byte  t*512 + ((col*2) ^ ((t&7)<<4)).
__global__ __launch_bounds__(512, 2) void gemmQ_kernel(
    const __hip_bfloat16* __restrict__ Aq, const __hip_bfloat16* __restrict__ Wt,
    const __hip_bfloat16* __restrict__ Vbf, const float* __restrict__ ksum,
    const float* __restrict__ carry, float* __restrict__ outp) {
  extern __shared__ char lds[];
  int lin = blockIdx.x;
  int wg  = (lin & 7) * 32 + (lin >> 3);
  int by  = wg & 3, bx = wg >> 2;
  const int m0 = bx * 256, n0 = by * 256;
  const __hip_bfloat16* Ag = Aq + (size_t)m0 * DIN;
  const __hip_bfloat16* Bg = Wt + (size_t)n0 * DIN;  // Wq half

  const int tid = threadIdx.x;
  const int wv = tid >> 6, lane = tid & 63;
  const int wm = (wv >> 2) * 128, wn = (wv & 3) * 64;
  const int fq = lane >> 4, fr = lane & 15;

  f32x4 acc[8][4] = {};
  gemm_core(Ag, Bg, lds, tid, wm, wn, fq, fr, acc);

  // --- stage V tile (rows m0..m0+255, cols n0..n0+255) into LDS ---
  const int b = m0 >> 11, t0 = m0 & 2047;
#pragma unroll
  for (int j = 0; j < 16; ++j) {
    int c = tid + j * 512;          // 8192 16B-chunks = 128KB
    int row = c >> 5, s = c & 31;   // 32 chunks per 512B row
    int chn = s ^ (row & 7);        // inverse swizzle on global source
    gload16(Vbf + (size_t)(m0 + row) * Dd + n0 + chn * 8, lds + c * 16);
  }
  asm volatile("s_waitcnt vmcnt(0)" ::: "memory");
  bar();

  // --- in-tile scan: 1024 (chunk,col) tasks, 2 per thread ---
#pragma unroll
  for (int p = 0; p < 2; ++p) {
    int task = tid + p * 512;
    int col = task & 255, cc = task >> 8;     // cc in 0..3
    float s = carry[((size_t)b * NC + (t0 >> 6) + cc) * Dd + n0 + col];
    const float* kp = ksum + (size_t)b * Tt + t0 + cc * 64;
    for (int i = 0; i < CL; ++i) {
      int t = cc * 64 + i;
      int addr = t * 512 + ((col * 2) ^ ((t & 7) << 4));
      unsigned short* sp = (unsigned short*)(lds + addr);
      float v = bf16_to_f32(*sp);
      float kv = kp[i];
      if (t0 == 0 && cc == 0 && i == 0) kv = 0.f;  // global t==0
      s = s * GAMMA + kv * v;
      *sp = (unsigned short)(__bfloat16_as_ushort(__float2bfloat16(s)));
    }
  }
  bar();

  // --- out = Q * S, fp32 ---
#pragma unroll
  for (int mi = 0; mi < 8; ++mi) {
#pragma unroll
    for (int ni = 0; ni < 4; ++ni) {
      f32x4 v = acc[mi][ni];
      int row = wm + mi * 16 + fq * 4;
      int col = wn + ni * 16 + fr;
#pragma unroll
      for (int j = 0; j < 4; ++j) {
        int r = row + j;
        int addr = r * 512 + ((col * 2) ^ ((r & 7) << 4));
        float S = bf16_to_f32(*(const unsigned short*)(lds + addr));
        outp[(size_t)(m0 + r) * Dd + n0 + col] = v[j] * S;
      }
    }
  }
}

// ---- K5: per-chunk local scan end values E[b][c][d] (R7 known-good) ------
__global__ void scanA_kernel(const __hip_bfloat16* __restrict__ Vbf,
                             const float* __restrict__ ksum,
                             float* __restrict__ E) {
  int b = blockIdx.x, c = blockIdx.y;
  int d = blockIdx.z * 256 + threadIdx.x;
  const __hip_bfloat16* Vp = Vbf + ((size_t)(b * Tt + c * CL) * Dd) + d;
  const float* kp = ksum + b * Tt + c * CL;
  float s = 0.f;
#pragma unroll 8
  for (int t = 0; t < CL; ++t) {
    float u = kp[t] * __bfloat162float(Vp[(size_t)t * Dd]);
    if (c == 0 && t == 0) u = 0.f;
    s = s * GAMMA + u;
  }
  E[((size_t)b * NC + c) * Dd + d] = s;
}

// ---- K6: compose carries across chunks (R7 known-good) -------------------
__global__ void scanB_kernel(const float* __restrict__ E, float* __restrict__ carry,
                             float gCL) {
  int b = blockIdx.x;
  int d = blockIdx.y * 256 + threadIdx.x;
  float send = 0.f;
  for (int c = 0; c < NC; ++c) {
    size_t idx = ((size_t)b * NC + c) * Dd + d;
    float e = E[idx];
    carry[idx] = send;          // S at end of chunk c-1
    send = e + gCL * send;
  }
}

extern "C" void kernel_launch(void* const* d_in, const int* in_sizes, int n_in,
                              void* d_out, int out_size, void* d_ws, size_t ws_size,
                              hipStream_t stream) {
  (void)in_sizes; (void)n_in; (void)out_size; (void)ws_size;
  const float* xq = (const float*)d_in[0];
  const float* xk = (const float*)d_in[1];
  const float* xv = (const float*)d_in[2];
  const float* Wq = (const float*)d_in[3];
  const float* Wk = (const float*)d_in[4];
  const float* Wv = (const float*)d_in[5];
  float* outp = (float*)d_out;

  char* ws = (char*)d_ws;
  size_t off = 0;
  auto alloc = [&](size_t bytes) {
    char* p = ws + off;
    off += (bytes + 255) & ~(size_t)255;
    return p;
  };
  __hip_bfloat16* xq_bf = (__hip_bfloat16*)alloc((size_t)Mm * DIN * 2);
  __hip_bfloat16* xv_bf = (__hip_bfloat16*)alloc((size_t)Mm * DIN * 2);
  __hip_bfloat16* Wt    = (__hip_bfloat16*)alloc((size_t)2 * DIN * Dd * 2);
  __hip_bfloat16* Vbf   = (__hip_bfloat16*)alloc((size_t)Mm * Dd * 2);
  float* wsum  = (float*)alloc((size_t)DIN * 4);
  float* ksum  = (float*)alloc((size_t)Mm * 4);
  float* E     = (float*)alloc((size_t)Bb * NC * Dd * 4);
  float* carry = (float*)alloc((size_t)Bb * NC * Dd * 4);

  double g = 1.0;
  for (int i = 0; i < CL; ++i) g *= (double)GAMMA;
  float gCL = (float)g;

  (void)hipFuncSetAttribute((const void*)gemmV_kernel,
                            hipFuncAttributeMaxDynamicSharedMemorySize, 131072);
  (void)hipFuncSetAttribute((const void*)gemmQ_kernel,
                            hipFuncAttributeMaxDynamicSharedMemorySize, 131072);

  prep_kernel<<<256 + 2048, 256, 0, stream>>>(Wq, Wk, Wv, wsum, Wt);
  castksum_kernel<<<dim3(Mm * DIN / 8 / 256, 3), 256, 0, stream>>>(
      xq, xk, xv, wsum, xq_bf, xv_bf, ksum);
  gemmV_kernel<<<256, 512, 131072, stream>>>(xv_bf, Wt, Vbf);
  scanA_kernel<<<dim3(Bb, NC, Dd / 256), 256, 0, stream>>>(Vbf, ksum, E);
  scanB_kernel<<<dim3(Bb, Dd / 256), 256, 0, stream>>>(E, carry, gCL);
  gemmQ_kernel<<<256, 512, 131072, stream>>>(xq_bf, Wt, Vbf, ksum, carry, outp);
}

// Round 13
// 143.579 us; speedup vs baseline: 1.6438x; 1.0259x over previous
//
#include <hip/hip_runtime.h>
#include <hip/hip_bf16.h>

#define GAMMA 0.9865f

typedef __attribute__((ext_vector_type(8))) short bf16x8;
typedef __attribute__((ext_vector_type(4))) float f32x4;

static constexpr int Bb  = 8;
static constexpr int Tt  = 2048;
static constexpr int DIN = 1024;
static constexpr int Dd  = 1024;
static constexpr int Mm  = Bb * Tt;      // 16384
static constexpr int CL  = 64;           // chunk length for scan
static constexpr int NC  = Tt / CL;      // 32 chunks
static constexpr int NT  = DIN / 64;     // 16 K-tiles of BK=64

__device__ __forceinline__ void gload16(const void* g, void* l) {
  __builtin_amdgcn_global_load_lds(
      (const __attribute__((address_space(1))) void*)g,
      (__attribute__((address_space(3))) void*)l, 16, 0, 0);
}

__device__ __forceinline__ void bar() {
  asm volatile("" ::: "memory");
  __builtin_amdgcn_s_barrier();
  asm volatile("" ::: "memory");
}

__device__ __forceinline__ float bf16_to_f32(unsigned short u) {
  return __uint_as_float(((unsigned int)u) << 16);
}

// ---- K1: merged prep: wsum (blocks 0..255) + Wt transpose (256..2303) ----
__global__ __launch_bounds__(256) void prep_kernel(
    const float* __restrict__ Wq, const float* __restrict__ Wk,
    const float* __restrict__ Wv, float* __restrict__ wsum,
    __hip_bfloat16* __restrict__ Wt) {
  int bid = blockIdx.x;
  if (bid < 256) {
    int row  = bid * 4 + (threadIdx.x >> 6);
    int lane = threadIdx.x & 63;
    const float4* rp = (const float4*)(Wk + (size_t)row * DIN);
    float s = 0.f;
#pragma unroll
    for (int i = 0; i < 4; ++i) {
      float4 v = rp[lane + i * 64];
      s += v.x + v.y + v.z + v.w;
    }
    for (int off = 32; off; off >>= 1) s += __shfl_down(s, off);
    if (lane == 0) wsum[row] = s;
    return;
  }
  int wid = bid - 256;
  int z = wid >> 10, rem = wid & 1023;
  int kb = rem & 31, nb = rem >> 5;
  const float* W = z ? Wv : Wq;
  __hip_bfloat16* outp = Wt + (size_t)z * DIN * Dd;
  __shared__ float tile[32][33];
  int k0 = kb * 32, n0 = nb * 32;
  int tx = threadIdx.x & 31, ty = threadIdx.x >> 5;
#pragma unroll
  for (int i = 0; i < 4; ++i)
    tile[ty + i * 8][tx] = W[(size_t)(k0 + ty + i * 8) * Dd + n0 + tx];
  __syncthreads();
#pragma unroll
  for (int i = 0; i < 4; ++i)
    outp[(size_t)(n0 + ty + i * 8) * DIN + k0 + tx] =
        __float2bfloat16(tile[tx][ty + i * 8]);
}

// ---- K2: merged cast (y=0,1) + ksum (y=2) — at HBM floor -----------------
__global__ __launch_bounds__(256) void castksum_kernel(
    const float* __restrict__ xq, const float* __restrict__ xk,
    const float* __restrict__ xv, const float* __restrict__ wsum,
    __hip_bfloat16* __restrict__ oq, __hip_bfloat16* __restrict__ ov,
    float* __restrict__ ksum) {
  int y = blockIdx.y;
  if (y < 2) {
    const float* src = y ? xv : xq;
    __hip_bfloat16* dst = y ? ov : oq;
    size_t i = (size_t)blockIdx.x * 256 + threadIdx.x;
    const float4* p = (const float4*)src;
    float4 a = p[i * 2], b = p[i * 2 + 1];
    union { __hip_bfloat16 h[8]; bf16x8 v; } u;
    u.h[0] = __float2bfloat16(a.x); u.h[1] = __float2bfloat16(a.y);
    u.h[2] = __float2bfloat16(a.z); u.h[3] = __float2bfloat16(a.w);
    u.h[4] = __float2bfloat16(b.x); u.h[5] = __float2bfloat16(b.y);
    u.h[6] = __float2bfloat16(b.z); u.h[7] = __float2bfloat16(b.w);
    ((bf16x8*)dst)[i] = u.v;
    return;
  }
  if (blockIdx.x >= Mm / 4) return;
  int row  = blockIdx.x * 4 + (threadIdx.x >> 6);
  int lane = threadIdx.x & 63;
  const float4* rp = (const float4*)(xk + (size_t)row * DIN);
  const float4* wp = (const float4*)wsum;
  float s = 0.f;
#pragma unroll
  for (int i = 0; i < 4; ++i) {
    float4 a = rp[lane + i * 64];
    float4 w = wp[lane + i * 64];
    s += a.x * w.x + a.y * w.y + a.z * w.z + a.w * w.w;
  }
  for (int off = 32; off; off >>= 1) s += __shfl_down(s, off);
  if (lane == 0) ksum[row] = s;
}

// ---- GEMM core: R7-verified 8-phase K-loop (conflicts=0, vmcnt(4)/tile) --
__device__ __forceinline__ void stage_half(const __hip_bfloat16* g, char* l, int tid) {
#pragma unroll
  for (int j = 0; j < 2; ++j) {
    int c = tid + j * 512;
    int row = c >> 3, ch = c & 7;
    gload16(g + (size_t)row * DIN + ((ch ^ (row & 7)) << 3), l + c * 16);
  }
}

__device__ __forceinline__ bf16x8 lds_frag(const char* base, int row, int kc) {
  return *(const bf16x8*)(base + (((row << 3) + (kc ^ (row & 7))) << 4));
}

#define MFMA_QUAD(MLO, NLO)                                                  \
  _Pragma("unroll") for (int mi = 0; mi < 4; ++mi)                           \
  _Pragma("unroll") for (int ni = 0; ni < 2; ++ni)                           \
  _Pragma("unroll") for (int ks = 0; ks < 2; ++ks)                           \
      acc[(MLO) + mi][(NLO) + ni] = __builtin_amdgcn_mfma_f32_16x16x32_bf16( \
          a[(MLO) + mi][ks], b[(NLO) + ni][ks], acc[(MLO) + mi][(NLO) + ni], 0, 0, 0);

__device__ __forceinline__ void gemm_core(const __hip_bfloat16* Ag,
                                          const __hip_bfloat16* Bg, char* lds,
                                          int tid, int wm, int wn, int fq, int fr,
                                          f32x4 (&acc)[8][4]) {
  stage_half(Ag,                  lds,                 tid);
  stage_half(Ag + 128 * DIN,      lds + 16384,         tid);
  stage_half(Bg,                  lds + 32768,         tid);
  stage_half(Bg + 128 * DIN,      lds + 49152,         tid);
  stage_half(Ag + 64,             lds + 65536,         tid);
  stage_half(Ag + 128 * DIN + 64, lds + 65536 + 16384, tid);
  asm volatile("s_waitcnt vmcnt(4)" ::: "memory");
  bar();

  for (int t = 0; t < NT; ++t) {
    char* buf  = lds + (t & 1) * 65536;
    char* bufN = lds + ((t + 1) & 1) * 65536;
    const char* At = buf;
    const char* Bt = buf + 32768;
    bf16x8 a[8][2], b[4][2];

#pragma unroll
    for (int mi = 0; mi < 4; ++mi)
#pragma unroll
      for (int ks = 0; ks < 2; ++ks)
        a[mi][ks] = lds_frag(At, wm + mi * 16 + fr, ks * 4 + fq);
#pragma unroll
    for (int ni = 0; ni < 2; ++ni)
#pragma unroll
      for (int ks = 0; ks < 2; ++ks)
        b[ni][ks] = lds_frag(Bt, wn + ni * 16 + fr, ks * 4 + fq);
    if (t + 1 < NT) stage_half(Bg + (size_t)(t + 1) * 64, bufN + 32768, tid);
    bar();
    __builtin_amdgcn_s_setprio(1);
    MFMA_QUAD(0, 0);
    __builtin_amdgcn_s_setprio(0);
    bar();

#pragma unroll
    for (int mi = 4; mi < 8; ++mi)
#pragma unroll
      for (int ks = 0; ks < 2; ++ks)
        a[mi][ks] = lds_frag(At, wm + mi * 16 + fr, ks * 4 + fq);
    if (t + 1 < NT)
      stage_half(Bg + 128 * DIN + (size_t)(t + 1) * 64, bufN + 49152, tid);
    bar();
    __builtin_amdgcn_s_setprio(1);
    MFMA_QUAD(4, 0);
    __builtin_amdgcn_s_setprio(0);
    bar();

#pragma unroll
    for (int ni = 2; ni < 4; ++ni)
#pragma unroll
      for (int ks = 0; ks < 2; ++ks)
        b[ni][ks] = lds_frag(Bt, wn + ni * 16 + fr, ks * 4 + fq);
    if (t + 2 < NT) stage_half(Ag + (size_t)(t + 2) * 64, buf, tid);
    bar();
    __builtin_amdgcn_s_setprio(1);
    MFMA_QUAD(0, 2);
    __builtin_amdgcn_s_setprio(0);
    bar();

    if (t + 2 < NT)
      stage_half(Ag + 128 * DIN + (size_t)(t + 2) * 64, buf + 16384, tid);
    if (t + 1 < NT) {
      if (t + 2 < NT) asm volatile("s_waitcnt vmcnt(4)" ::: "memory");
      else            asm volatile("s_waitcnt vmcnt(0)" ::: "memory");
    }
    bar();
    __builtin_amdgcn_s_setprio(1);
    MFMA_QUAD(4, 2);
    __builtin_amdgcn_s_setprio(0);
    bar();
  }
}

// ---- K3a: V GEMM + fused scanA epilogue (grid 256) -----------------------
// After K-loop: store V bf16 to global AND stash it in the freed 128KB LDS
// (layout: r*512 + ((col*2)^((r&7)<<4)), same as gemmQ), then compute the 4
// chunk-end values E for this block's 4 chunks x 256 cols in-LDS.
__global__ __launch_bounds__(512, 2) void gemmV_kernel(
    const __hip_bfloat16* __restrict__ Av, const __hip_bfloat16* __restrict__ Wt,
    const float* __restrict__ ksum, __hip_bfloat16* __restrict__ Vbf,
    float* __restrict__ E) {
  extern __shared__ char lds[];
  int lin = blockIdx.x;
  int wg  = (lin & 7) * 32 + (lin >> 3);   // 256 blocks, bijective
  int by  = wg & 3, bx = wg >> 2;
  const int m0 = bx * 256, n0 = by * 256;
  const __hip_bfloat16* Ag = Av + (size_t)m0 * DIN;
  const __hip_bfloat16* Bg = Wt + ((size_t)Dd + n0) * DIN;  // Wv half

  const int tid = threadIdx.x;
  const int wv = tid >> 6, lane = tid & 63;
  const int wm = (wv >> 2) * 128, wn = (wv & 3) * 64;
  const int fq = lane >> 4, fr = lane & 15;

  f32x4 acc[8][4] = {};
  gemm_core(Ag, Bg, lds, tid, wm, wn, fq, fr, acc);

  // global store + LDS stash (bf16, swizzled)
#pragma unroll
  for (int mi = 0; mi < 8; ++mi) {
#pragma unroll
    for (int ni = 0; ni < 4; ++ni) {
      f32x4 v = acc[mi][ni];
      int row = wm + mi * 16 + fq * 4;
      int col = wn + ni * 16 + fr;
#pragma unroll
      for (int j = 0; j < 4; ++j) {
        int r = row + j;
        unsigned short h = __bfloat16_as_ushort(__float2bfloat16(v[j]));
        Vbf[(size_t)(m0 + r) * Dd + n0 + col] = __ushort_as_bfloat16(h);
        *(unsigned short*)(lds + r * 512 + ((col * 2) ^ ((r & 7) << 4))) = h;
      }
    }
  }
  bar();

  // in-tile chunk scans -> E  (1024 tasks = 4 chunks x 256 cols, 2/thread)
  const int b = m0 >> 11, t0 = m0 & 2047;
#pragma unroll
  for (int p = 0; p < 2; ++p) {
    int task = tid + p * 512;
    int col = task & 255, cc = task >> 8;
    const float* kp = ksum + (size_t)b * Tt + t0 + cc * 64;
    float s = 0.f;
    for (int i = 0; i < CL; ++i) {
      int t = cc * 64 + i;
      float v = bf16_to_f32(
          *(const unsigned short*)(lds + t * 512 + ((col * 2) ^ ((t & 7) << 4))));
      float kv = kp[i];
      if (t0 == 0 && cc == 0 && i == 0) kv = 0.f;
      s = s * GAMMA + kv * v;
    }
    E[((size_t)b * NC + (t0 >> 6) + cc) * Dd + n0 + col] = s;
  }
}

// ---- K3b: Q GEMM with fused scan+final epilogue (grid 256) — R12 verified-
__global__ __launch_bounds__(512, 2) void gemmQ_kernel(
    const __hip_bfloat16* __restrict__ Aq, const __hip_bfloat16* __restrict__ Wt,
    const __hip_bfloat16* __restrict__ Vbf, const float* __restrict__ ksum,
    const float* __restrict__ carry, float* __restrict__ outp) {
  extern __shared__ char lds[];
  int lin = blockIdx.x;
  int wg  = (lin & 7) * 32 + (lin >> 3);
  int by  = wg & 3, bx = wg >> 2;
  const int m0 = bx * 256, n0 = by * 256;
  const __hip_bfloat16* Ag = Aq + (size_t)m0 * DIN;
  const __hip_bfloat16* Bg = Wt + (size_t)n0 * DIN;  // Wq half

  const int tid = threadIdx.x;
  const int wv = tid >> 6, lane = tid & 63;
  const int wm = (wv >> 2) * 128, wn = (wv & 3) * 64;
  const int fq = lane >> 4, fr = lane & 15;

  f32x4 acc[8][4] = {};
  gemm_core(Ag, Bg, lds, tid, wm, wn, fq, fr, acc);

  // --- stage V tile into LDS (swizzled source, linear dest) ---
  const int b = m0 >> 11, t0 = m0 & 2047;
#pragma unroll
  for (int j = 0; j < 16; ++j) {
    int c = tid + j * 512;
    int row = c >> 5, s = c & 31;
    int chn = s ^ (row & 7);
    gload16(Vbf + (size_t)(m0 + row) * Dd + n0 + chn * 8, lds + c * 16);
  }
  asm volatile("s_waitcnt vmcnt(0)" ::: "memory");
  bar();

  // --- in-tile scan with carry, S stored bf16 in place ---
#pragma unroll
  for (int p = 0; p < 2; ++p) {
    int task = tid + p * 512;
    int col = task & 255, cc = task >> 8;
    float s = carry[((size_t)b * NC + (t0 >> 6) + cc) * Dd + n0 + col];
    const float* kp = ksum + (size_t)b * Tt + t0 + cc * 64;
    for (int i = 0; i < CL; ++i) {
      int t = cc * 64 + i;
      int addr = t * 512 + ((col * 2) ^ ((t & 7) << 4));
      unsigned short* sp = (unsigned short*)(lds + addr);
      float v = bf16_to_f32(*sp);
      float kv = kp[i];
      if (t0 == 0 && cc == 0 && i == 0) kv = 0.f;
      s = s * GAMMA + kv * v;
      *sp = __bfloat16_as_ushort(__float2bfloat16(s));
    }
  }
  bar();

  // --- out = Q * S, fp32 ---
#pragma unroll
  for (int mi = 0; mi < 8; ++mi) {
#pragma unroll
    for (int ni = 0; ni < 4; ++ni) {
      f32x4 v = acc[mi][ni];
      int row = wm + mi * 16 + fq * 4;
      int col = wn + ni * 16 + fr;
#pragma unroll
      for (int j = 0; j < 4; ++j) {
        int r = row + j;
        float S = bf16_to_f32(
            *(const unsigned short*)(lds + r * 512 + ((col * 2) ^ ((r & 7) << 4))));
        outp[(size_t)(m0 + r) * Dd + n0 + col] = v[j] * S;
      }
    }
  }
}

// ---- K6: compose carries across chunks (R7 known-good) -------------------
__global__ void scanB_kernel(const float* __restrict__ E, float* __restrict__ carry,
                             float gCL) {
  int b = blockIdx.x;
  int d = blockIdx.y * 256 + threadIdx.x;
  float send = 0.f;
  for (int c = 0; c < NC; ++c) {
    size_t idx = ((size_t)b * NC + c) * Dd + d;
    float e = E[idx];
    carry[idx] = send;          // S at end of chunk c-1
    send = e + gCL * send;
  }
}

extern "C" void kernel_launch(void* const* d_in, const int* in_sizes, int n_in,
                              void* d_out, int out_size, void* d_ws, size_t ws_size,
                              hipStream_t stream) {
  (void)in_sizes; (void)n_in; (void)out_size; (void)ws_size;
  const float* xq = (const float*)d_in[0];
  const float* xk = (const float*)d_in[1];
  const float* xv = (const float*)d_in[2];
  const float* Wq = (const float*)d_in[3];
  const float* Wk = (const float*)d_in[4];
  const float* Wv = (const float*)d_in[5];
  float* outp = (float*)d_out;

  char* ws = (char*)d_ws;
  size_t off = 0;
  auto alloc = [&](size_t bytes) {
    char* p = ws + off;
    off += (bytes + 255) & ~(size_t)255;
    return p;
  };
  __hip_bfloat16* xq_bf = (__hip_bfloat16*)alloc((size_t)Mm * DIN * 2);
  __hip_bfloat16* xv_bf = (__hip_bfloat16*)alloc((size_t)Mm * DIN * 2);
  __hip_bfloat16* Wt    = (__hip_bfloat16*)alloc((size_t)2 * DIN * Dd * 2);
  __hip_bfloat16* Vbf   = (__hip_bfloat16*)alloc((size_t)Mm * Dd * 2);
  float* wsum  = (float*)alloc((size_t)DIN * 4);
  float* ksum  = (float*)alloc((size_t)Mm * 4);
  float* E     = (float*)alloc((size_t)Bb * NC * Dd * 4);
  float* carry = (float*)alloc((size_t)Bb * NC * Dd * 4);

  double g = 1.0;
  for (int i = 0; i < CL; ++i) g *= (double)GAMMA;
  float gCL = (float)g;

  (void)hipFuncSetAttribute((const void*)gemmV_kernel,
                            hipFuncAttributeMaxDynamicSharedMemorySize, 131072);
  (void)hipFuncSetAttribute((const void*)gemmQ_kernel,
                            hipFuncAttributeMaxDynamicSharedMemorySize, 131072);

  prep_kernel<<<256 + 2048, 256, 0, stream>>>(Wq, Wk, Wv, wsum, Wt);
  castksum_kernel<<<dim3(Mm * DIN / 8 / 256, 3), 256, 0, stream>>>(
      xq, xk, xv, wsum, xq_bf, xv_bf, ksum);
  gemmV_kernel<<<256, 512, 131072, stream>>>(xv_bf, Wt, ksum, Vbf, E);
  scanB_kernel<<<dim3(Bb, Dd / 256), 256, 0, stream>>>(E, carry, gCL);
  gemmQ_kernel<<<256, 512, 131072, stream>>>(xq_bf, Wt, Vbf, ksum, carry, outp);
}